// Round 1
// baseline (303.581 us; speedup 1.0000x reference)
//
#include <hip/hip_runtime.h>

// PillarScatter: feat [B=8, V=16384, C=64] f32, coords [B, V, 3] i32 (x,y,z)
// out [B, C, 512, 512] f32; out[b,c,y,x] = feat[b,v,c] for the LAST v mapping
// to (y,x) (numpy fancy-assign semantics), 0 elsewhere.
//
// Strategy: invert scatter -> gather.
//   pass 1: winner[b, y*512+x] = max v landing there (atomicMax, det.)
//   pass 2: one thread per (b, cell) streams all 64 channels to out
//           (coalesced 256B stores per wave per channel).

static constexpr int GX = 512;
static constexpr int GY = 512;
static constexpr int NCELL = GX * GY;   // 262144 = 2^18
static constexpr int B = 8;
static constexpr int V = 16384;         // 2^14
static constexpr int C = 64;

__global__ __launch_bounds__(256) void ps_winner(const int* __restrict__ coords,
                                                 int* __restrict__ winner) {
    int idx = blockIdx.x * 256 + threadIdx.x;       // over B*V = 131072
    int x = coords[idx * 3 + 0];
    int y = coords[idx * 3 + 1];
    if ((unsigned)x >= (unsigned)GX || (unsigned)y >= (unsigned)GY) return;
    int b = idx >> 14;                              // idx / V
    int v = idx & (V - 1);
    atomicMax(&winner[(b << 18) + y * GX + x], v);  // last occurrence wins
}

__global__ __launch_bounds__(256) void ps_gather(const float4* __restrict__ feat,
                                                 const int* __restrict__ winner,
                                                 float* __restrict__ out) {
    int tid = blockIdx.x * 256 + threadIdx.x;       // over B*NCELL = 2M
    int b = tid >> 18;                              // tid / NCELL
    int cell = tid & (NCELL - 1);
    int w = winner[tid];
    float* obase = out + ((long long)b << 24) + cell;   // b*C*NCELL + cell
    if (w >= 0) {
        // feature row: feat + (b*V + w)*C floats = (b*V + w)*16 float4s
        const float4* frow = feat + ((long long)((b << 14) + w) << 4);
#pragma unroll
        for (int c4 = 0; c4 < 16; ++c4) {
            float4 f = frow[c4];
            obase[(c4 * 4 + 0) * (long long)NCELL] = f.x;
            obase[(c4 * 4 + 1) * (long long)NCELL] = f.y;
            obase[(c4 * 4 + 2) * (long long)NCELL] = f.z;
            obase[(c4 * 4 + 3) * (long long)NCELL] = f.w;
        }
    } else {
#pragma unroll
        for (int c = 0; c < C; ++c)
            obase[(long long)c * NCELL] = 0.0f;
    }
}

extern "C" void kernel_launch(void* const* d_in, const int* in_sizes, int n_in,
                              void* d_out, int out_size, void* d_ws, size_t ws_size,
                              hipStream_t stream) {
    const float* feat  = (const float*)d_in[0];
    const int* coords  = (const int*)d_in[1];
    float* out         = (float*)d_out;
    int* winner        = (int*)d_ws;                 // B*NCELL ints = 8 MB

    // winner = -1 everywhere (0xFF bytes)
    hipMemsetAsync(winner, 0xFF, (size_t)B * NCELL * sizeof(int), stream);
    ps_winner<<<(B * V) / 256, 256, 0, stream>>>(coords, winner);
    ps_gather<<<(B * NCELL) / 256, 256, 0, stream>>>((const float4*)feat, winner, out);
}

// Round 3
// 117.295 us; speedup vs baseline: 2.5882x; 2.5882x over previous
//
#include <hip/hip_runtime.h>

// PillarScatter: feat [B=8, V=16384, C=64] f32, coords [B, V, 3] i32 (x,y,z)
// out [B, C, 512, 512] f32; out[b,c,y,x] = feat[b,v,c] for the LAST v mapping
// to (y,x) (numpy fancy-assign semantics), 0 elsewhere.
//
// v2b: gather writes 4 cells/thread with a 4x4 register transpose so each
// wave's per-channel store is 1KB contiguous (was 256B). Nontemporal stores
// via native clang vectors (HIP float4 is not accepted by the builtin).
// Invalid cells load a zeroed dummy row (uniform address, cache-hot).

typedef float f32x4 __attribute__((ext_vector_type(4)));
typedef int   i32x4 __attribute__((ext_vector_type(4)));

static constexpr int GX = 512;
static constexpr int GY = 512;
static constexpr int NCELL = GX * GY;   // 262144 = 2^18
static constexpr int B = 8;
static constexpr int V = 16384;         // 2^14
static constexpr int C = 64;

__global__ __launch_bounds__(256) void ps_winner(const int* __restrict__ coords,
                                                 int* __restrict__ winner) {
    int idx = blockIdx.x * 256 + threadIdx.x;       // over B*V = 131072
    int x = coords[idx * 3 + 0];
    int y = coords[idx * 3 + 1];
    if ((unsigned)x >= (unsigned)GX || (unsigned)y >= (unsigned)GY) return;
    int b = idx >> 14;                              // idx / V
    int v = idx & (V - 1);
    atomicMax(&winner[(b << 18) + y * GX + x], v);  // last occurrence wins
}

__global__ __launch_bounds__(256) void ps_gather4(const f32x4* __restrict__ feat,
                                                  const i32x4* __restrict__ winner4,
                                                  const f32x4* __restrict__ dummy,
                                                  float* __restrict__ out) {
    int tid = blockIdx.x * 256 + threadIdx.x;       // over B*NCELL/4 = 524288
    int b = tid >> 16;                              // tid / (NCELL/4)
    int cell4 = (tid & ((NCELL / 4) - 1)) * 4;      // first of 4 consecutive cells

    i32x4 w = winner4[tid];

    // Row pointers; invalid -> shared zeroed dummy row (uniform, cache-hot).
    const f32x4* r0 = (w.x >= 0) ? feat + ((long long)((b << 14) + w.x) << 4) : dummy;
    const f32x4* r1 = (w.y >= 0) ? feat + ((long long)((b << 14) + w.y) << 4) : dummy;
    const f32x4* r2 = (w.z >= 0) ? feat + ((long long)((b << 14) + w.z) << 4) : dummy;
    const f32x4* r3 = (w.w >= 0) ? feat + ((long long)((b << 14) + w.w) << 4) : dummy;

    float* obase = out + ((long long)b << 24) + cell4;  // b*C*NCELL + cell4

#pragma unroll
    for (int c4 = 0; c4 < 16; ++c4) {
        f32x4 f0 = r0[c4];
        f32x4 f1 = r1[c4];
        f32x4 f2 = r2[c4];
        f32x4 f3 = r3[c4];
        // 4x4 transpose: channel c = c4*4+e gets {f0[e], f1[e], f2[e], f3[e]}
        f32x4 s0 = {f0.x, f1.x, f2.x, f3.x};
        f32x4 s1 = {f0.y, f1.y, f2.y, f3.y};
        f32x4 s2 = {f0.z, f1.z, f2.z, f3.z};
        f32x4 s3 = {f0.w, f1.w, f2.w, f3.w};
        f32x4* p0 = (f32x4*)(obase + (long long)(c4 * 4 + 0) * NCELL);
        f32x4* p1 = (f32x4*)(obase + (long long)(c4 * 4 + 1) * NCELL);
        f32x4* p2 = (f32x4*)(obase + (long long)(c4 * 4 + 2) * NCELL);
        f32x4* p3 = (f32x4*)(obase + (long long)(c4 * 4 + 3) * NCELL);
        __builtin_nontemporal_store(s0, p0);
        __builtin_nontemporal_store(s1, p1);
        __builtin_nontemporal_store(s2, p2);
        __builtin_nontemporal_store(s3, p3);
    }
}

extern "C" void kernel_launch(void* const* d_in, const int* in_sizes, int n_in,
                              void* d_out, int out_size, void* d_ws, size_t ws_size,
                              hipStream_t stream) {
    const float* feat  = (const float*)d_in[0];
    const int* coords  = (const int*)d_in[1];
    float* out         = (float*)d_out;
    int* winner        = (int*)d_ws;                              // 8 MB
    float* dummy       = (float*)((char*)d_ws + (size_t)B * NCELL * sizeof(int)); // 256 B

    (void)hipMemsetAsync(winner, 0xFF, (size_t)B * NCELL * sizeof(int), stream);
    (void)hipMemsetAsync(dummy, 0, C * sizeof(float), stream);
    ps_winner<<<(B * V) / 256, 256, 0, stream>>>(coords, winner);
    ps_gather4<<<(B * NCELL / 4) / 256, 256, 0, stream>>>(
        (const f32x4*)feat, (const i32x4*)winner, (const f32x4*)dummy, out);
}